// Round 1
// baseline (5180.106 us; speedup 1.0000x reference)
//
#include <hip/hip_runtime.h>

// ---------------------------------------------------------------------------
// arGDPmax_net: 80-step coupled GRU (SDC 128 rows / world 3968 rows, H=512)
// + segment-max coupling + per-step MLP head.
//
// Strategy:
//  - All matmuls: bf16 MFMA 16x16x32, fp32 accum. Weights pre-transposed to
//    WT[n][k] (K-contiguous) so A and B fragments are contiguous b128 LDS reads.
//  - wld gi term: (sh @ wld_Wi + bi) computed once per step on 128 rows (k_small),
//    gathered by seg_ids in the big kernel epilogue (halves the big GEMM).
//  - segment_max folded into k_big epilogue via flipped-uint atomicMax.
//  - Gate columns paired {c, c+512, c+1024} per block -> gates fused in epilogue.
//  - bf16 ring buffer (8 deep) of hidden states feeds a batched MLP kernel.
//  - XOR-swizzled LDS staging (row&7 ^ 16B-unit) -> conflict-free b128 reads.
// ---------------------------------------------------------------------------

typedef __attribute__((ext_vector_type(8))) short short8;
typedef __attribute__((ext_vector_type(4))) float f32x4;
typedef unsigned short u16;
typedef unsigned int u32;

#define DEV __device__ __forceinline__

constexpr int S  = 128;    // scenarios (sdc rows)
constexpr int NR = 4096;   // total rows (128 sdc + 3968 wld)
constexpr int H  = 512;
constexpr int TH = 1536;   // 3*H
constexpr int SLOT = NR * H;      // elems per state slot
constexpr int SEGSZ = S * H;      // elems per segmax buffer

struct P {
  const float *goals, *dyn, *ccls, *inte;
  const int *seg;
  const float *sdc_h0, *wld_h0;
  const float *golW, *golb;
  const float *sdcbi, *sdcbh, *wldbi, *wldbh;
  const float *sdco1b, *sdco2W, *sdco2b;
  const float *wldo1b, *wldo2W, *wldo2b;
  const float *sdcWi, *sdcWh, *wldWi, *wldWh, *sdco1W, *wldo1W;
  float *out;
  float *whf;      // [2][4096][512] f32 carried state
  u16   *ring;     // [8][4096][512] bf16 state history (MFMA A-operand source)
  u16   *enc;      // [4096][512] bf16 encoder output
  u16   *WT;       // 4 x [1536][512] bf16: sdcWiT, sdcWhT, wldWiT, wldWhT
  u16   *o1T;      // 2 x [512][512] bf16: sdc_o1T, wld_o1T
  float *G;        // [128][1536] f32: sh@wld_Wi + bi
  u32   *segb;     // [2][128][512] flipped-uint segmax buffers
  int t;
};

DEV u16 f2bf(float f) {                     // round-to-nearest-even f32->bf16
  u32 u = __float_as_uint(f);
  u32 r = u + 0x7FFFu + ((u >> 16) & 1u);
  return (u16)(r >> 16);
}
DEV u32 flipf(float f) {                    // monotone f32 -> u32 (for atomicMax)
  u32 u = __float_as_uint(f);
  return (u & 0x80000000u) ? ~u : (u | 0x80000000u);
}
DEV float unflip(u32 s) {
  u32 u = (s & 0x80000000u) ? (s & 0x7FFFFFFFu) : ~s;
  return __uint_as_float(u);
}
DEV float sigm(float x)  { return 1.0f / (1.0f + __expf(-x)); }
DEV float tanh_(float x) { return 2.0f / (1.0f + __expf(-2.0f * x)) - 1.0f; }

DEV f32x4 mfma16(short8 a, short8 b, f32x4 c) {
  return __builtin_amdgcn_mfma_f32_16x16x32_bf16(a, b, c, 0, 0, 0);
}

// Stage `rows` x 64 bf16 tile into LDS (128B rows) with XOR swizzle:
// LDS position (m, g) holds source 16B-unit (m, g ^ (m&7)).
DEV void stage_bf(u16* lds, const u16* src, int stride, int rows, int tid) {
  for (int u = tid; u < rows * 8; u += 256) {
    int m = u >> 3, g = u & 7, gs = g ^ (m & 7);
    *(short8*)(lds + (u << 3)) = *(const short8*)(src + m * stride + (gs << 3));
  }
}
// Same but source = flipped-uint segmax buffer (unflip + cvt to bf16). 64 rows.
DEV void stage_seg(u16* lds, const u32* src, int stride, int tid) {
  for (int u = tid; u < 512; u += 256) {
    int m = u >> 3, g = u & 7, gs = g ^ (m & 7);
    const u32* pp = src + m * stride + (gs << 3);
    short8 v;
#pragma unroll
    for (int e = 0; e < 8; ++e) v[e] = (short)f2bf(unflip(pp[e]));
    *(short8*)(lds + (u << 3)) = v;
  }
}
// Fragment read (8 bf16 along K) honoring the swizzle. Row stride 64 elems.
DEV short8 lds_frag(const u16* lds, int row, int g) {
  return *(const short8*)(lds + row * 64 + ((g ^ (row & 7)) << 3));
}
// 32-K-chunk variants (64B rows, XOR over row&3) for the MLP kernel.
DEV void stage_bf32(u16* lds, const u16* src, int stride, int rows, int tid) {
  for (int u = tid; u < rows * 4; u += 256) {
    int m = u >> 2, g = u & 3, gs = g ^ (m & 3);
    *(short8*)(lds + (u << 3)) = *(const short8*)(src + m * stride + (gs << 3));
  }
}
DEV short8 lds_frag32(const u16* lds, int row, int g) {
  return *(const short8*)(lds + row * 32 + ((g ^ (row & 3)) << 3));
}

// ---------------------------------------------------------------------------
// k_prep: weight transposes (f32 [K][N] -> bf16 [N][K]), encoder, h0 copy,
//         segbuf[0] clear.  Grid 1028 x 256.
// ---------------------------------------------------------------------------
__global__ __launch_bounds__(256) void k_prep(P p) {
  const int b = blockIdx.x, tid = threadIdx.x;
  __shared__ u16 lt[64 * 72];
  if (b < 896) {                               // transpose roles
    int nt, kt, Nn; const float* src; u16* dst;
    if (b < 768) {
      int m = b / 192, t2 = b % 192;
      nt = t2 % 24; kt = t2 / 24; Nn = TH;
      src = (m == 0) ? p.sdcWi : (m == 1) ? p.sdcWh : (m == 2) ? p.wldWi : p.wldWh;
      dst = p.WT + m * TH * H;
    } else {
      int bb = b - 768, m = bb / 64, t2 = bb % 64;
      nt = t2 % 8; kt = t2 / 8; Nn = H;
      src = m ? p.wldo1W : p.sdco1W;
      dst = p.o1T + m * H * H;
    }
    for (int it = 0; it < 16; ++it) {
      int kl = it * 4 + (tid >> 6), nl = tid & 63;
      lt[nl * 72 + kl] = f2bf(src[(kt * 64 + kl) * Nn + nt * 64 + nl]);
    }
    __syncthreads();
    for (int it = 0; it < 2; ++it) {
      int nl = it * 32 + (tid >> 3), k8 = (tid & 7) * 8;
      *(short8*)(dst + (nt * 64 + nl) * H + kt * 64 + k8) =
          *(const short8*)(lt + nl * 72 + k8);
    }
  } else if (b < 960) {                        // encoder: enc = [goals@W+b, dyn, ccls, int]
    int r0 = (b - 896) * 64;
    for (int i = 0; i < 128; ++i) {
      int idx = i * 256 + tid, row = r0 + (idx >> 9), c = idx & 511;
      float v;
      if (c < 128)      v = p.goals[row*2]*p.golW[c] + p.goals[row*2+1]*p.golW[128+c] + p.golb[c];
      else if (c < 256) v = p.dyn [row*128 + c - 128];
      else if (c < 384) v = p.ccls[row*128 + c - 256];
      else              v = p.inte[row*128 + c - 384];
      p.enc[row * H + c] = f2bf(v);
    }
  } else if (b < 1024) {                       // h0 -> whf[1] (f32) and ring[7] (bf16)
    int r0 = (b - 960) * 64;
    for (int i = 0; i < 128; ++i) {
      int idx = i * 256 + tid, row = r0 + (idx >> 9), c = idx & 511;
      float v = (row < S) ? p.sdc_h0[row * H + c] : p.wld_h0[(row - S) * H + c];
      p.whf[SLOT + row * H + c] = v;
      p.ring[7 * SLOT + row * H + c] = f2bf(v);
    }
  } else {                                     // clear segbuf[0]
    int base = (b - 1024) * 16384;
    for (int i = 0; i < 64; ++i) p.segb[base + i * 256 + tid] = 0u;
  }
}

// ---------------------------------------------------------------------------
// k_big0: step 0. gi = enc@WiT+bi (full matmul), gh = h0@WhT+bh, gates,
//         writes whf[0], ring[0], segmax -> segbuf[0].  Grid 512 (64 rt x 8 cg).
// ---------------------------------------------------------------------------
__global__ __launch_bounds__(256) void k_big0(P p) {
  const int b = blockIdx.x, tid = threadIdx.x;
  const int rt = b >> 3, cg = b & 7;
  const bool sdc = rt < 2;
  const int w = tid >> 6, lr = (tid >> 4) & 3, lc = tid & 15;
  __shared__ u16 ldsA[4096];
  __shared__ u16 ldsB[12288];
  const u16* WiT = p.WT + (sdc ? 0 : 2) * TH * H;
  const u16* WhT = p.WT + (sdc ? 1 : 3) * TH * H;

  f32x4 ai[3][4], ah[3][4];
  f32x4 zero = {0.f, 0.f, 0.f, 0.f};
#pragma unroll
  for (int g = 0; g < 3; ++g)
#pragma unroll
    for (int mt = 0; mt < 4; ++mt) { ai[g][mt] = zero; ah[g][mt] = zero; }

  for (int pass = 0; pass < 2; ++pass) {
    const u16* A  = pass ? (p.ring + 7 * SLOT + rt * 64 * H) : (p.enc + rt * 64 * H);
    const u16* BT = pass ? WhT : WiT;
    for (int kc = 0; kc < H; kc += 64) {
      __syncthreads();
      stage_bf(ldsA, A + kc, H, 64, tid);
#pragma unroll
      for (int g = 0; g < 3; ++g)
        stage_bf(ldsB + g * 4096, BT + (g * H + cg * 64) * H + kc, H, 64, tid);
      __syncthreads();
#pragma unroll
      for (int s2 = 0; s2 < 2; ++s2) {
        const int gk = s2 * 4 + lr;
        short8 av[4], bv[3];
#pragma unroll
        for (int mt = 0; mt < 4; ++mt) av[mt] = lds_frag(ldsA, mt * 16 + lc, gk);
#pragma unroll
        for (int g = 0; g < 3; ++g) bv[g] = lds_frag(ldsB + g * 4096, w * 16 + lc, gk);
#pragma unroll
        for (int g = 0; g < 3; ++g)
#pragma unroll
          for (int mt = 0; mt < 4; ++mt) {
            f32x4 r = pass ? ah[g][mt] : ai[g][mt];
            r = mfma16(av[mt], bv[g], r);
            if (pass) ah[g][mt] = r; else ai[g][mt] = r;
          }
      }
    }
  }
  const float* bi = sdc ? p.sdcbi : p.wldbi;
  const float* bh = sdc ? p.sdcbh : p.wldbh;
  const int col = cg * 64 + w * 16 + lc;
  const float bir = bi[col], biz = bi[H + col], bin = bi[2 * H + col];
  const float bhr = bh[col], bhz = bh[H + col], bhn = bh[2 * H + col];
#pragma unroll
  for (int mt = 0; mt < 4; ++mt)
#pragma unroll
    for (int i = 0; i < 4; ++i) {
      int grow = rt * 64 + mt * 16 + lr * 4 + i;
      float r = sigm(ai[0][mt][i] + bir + ah[0][mt][i] + bhr);
      float z = sigm(ai[1][mt][i] + biz + ah[1][mt][i] + bhz);
      float n = tanh_(ai[2][mt][i] + bin + r * (ah[2][mt][i] + bhn));
      float h = p.whf[SLOT + grow * H + col];
      float h2 = (1.f - z) * n + z * h;
      p.whf[grow * H + col] = h2;
      p.ring[grow * H + col] = f2bf(h2);
      if (!sdc) {
        int scen = p.seg[grow - S];
        atomicMax(p.segb + scen * H + col, flipf(h2));
      }
    }
}

// ---------------------------------------------------------------------------
// k_small(t): G = sh_{t-1} @ wld_WiT + bi  (128x1536), and clear segbuf[t&1].
// Grid 64 (2 rh x 32 ng), tile 64 rows x 48 cols.
// ---------------------------------------------------------------------------
__global__ __launch_bounds__(256) void k_small(P p) {
  const int b = blockIdx.x, tid = threadIdx.x;
  const int rh = b >> 5, ng = b & 31;
  const int w = tid >> 6, lr = (tid >> 4) & 3, lc = tid & 15;
  // clear segmax buffer for this step's k_big atomics
  u32* sb = p.segb + (p.t & 1) * SEGSZ;
#pragma unroll
  for (int i = 0; i < 4; ++i) sb[b * 1024 + i * 256 + tid] = 0u;

  __shared__ u16 ldsA[4096];
  __shared__ u16 ldsB[3072];
  const u16* A   = p.ring + ((p.t - 1) & 7) * SLOT + rh * 64 * H;
  const u16* WiT = p.WT + 2 * TH * H;          // wld_WiT
  f32x4 acc[3];
  f32x4 zero = {0.f, 0.f, 0.f, 0.f};
#pragma unroll
  for (int s3 = 0; s3 < 3; ++s3) acc[s3] = zero;

  for (int kc = 0; kc < H; kc += 64) {
    __syncthreads();
    stage_bf(ldsA, A + kc, H, 64, tid);
#pragma unroll
    for (int s3 = 0; s3 < 3; ++s3)
      stage_bf(ldsB + s3 * 1024, WiT + (ng * 48 + s3 * 16) * H + kc, H, 16, tid);
    __syncthreads();
#pragma unroll
    for (int s2 = 0; s2 < 2; ++s2) {
      const int gk = s2 * 4 + lr;
      short8 a = lds_frag(ldsA, w * 16 + lc, gk);
#pragma unroll
      for (int s3 = 0; s3 < 3; ++s3)
        acc[s3] = mfma16(a, lds_frag(ldsB + s3 * 1024, lc, gk), acc[s3]);
    }
  }
#pragma unroll
  for (int s3 = 0; s3 < 3; ++s3)
#pragma unroll
    for (int i = 0; i < 4; ++i) {
      int row = rh * 64 + w * 16 + lr * 4 + i;
      int ncol = ng * 48 + s3 * 16 + lc;
      p.G[row * TH + ncol] = acc[s3][i] + p.wldbi[ncol];
    }
}

// ---------------------------------------------------------------------------
// k_big(t): blocks 0..495: world GRU (gh GEMM + gather(G) + gates + segmax).
//           blocks 496..559: sdc GRU (gi from segmax, gh from sh).
// ---------------------------------------------------------------------------
__global__ __launch_bounds__(256) void k_big(P p) {
  const int b = blockIdx.x, tid = threadIdx.x;
  const int w = tid >> 6, lr = (tid >> 4) & 3, lc = tid & 15;
  __shared__ u16 ldsA[4096];
  __shared__ u16 ldsB[12288];
  const int tp = (p.t - 1) & 7, tn = p.t & 7;
  const float* whfP = p.whf + ((p.t - 1) & 1) * SLOT;
  float* whfN = p.whf + (p.t & 1) * SLOT;
  u16* ringN = p.ring + tn * SLOT;

  if (b < 496) {  // ---- world GRU ----
    const int rt = b / 8, cg = b % 8;
    const u16* A  = p.ring + tp * SLOT + (S + rt * 64) * H;
    const u16* BT = p.WT + 3 * TH * H;         // wld_WhT
    f32x4 acc[3][4];
    f32x4 zero = {0.f, 0.f, 0.f, 0.f};
#pragma unroll
    for (int g = 0; g < 3; ++g)
#pragma unroll
      for (int mt = 0; mt < 4; ++mt) acc[g][mt] = zero;

    for (int kc = 0; kc < H; kc += 64) {
      __syncthreads();
      stage_bf(ldsA, A + kc, H, 64, tid);
#pragma unroll
      for (int g = 0; g < 3; ++g)
        stage_bf(ldsB + g * 4096, BT + (g * H + cg * 64) * H + kc, H, 64, tid);
      __syncthreads();
#pragma unroll
      for (int s2 = 0; s2 < 2; ++s2) {
        const int gk = s2 * 4 + lr;
        short8 av[4], bv[3];
#pragma unroll
        for (int mt = 0; mt < 4; ++mt) av[mt] = lds_frag(ldsA, mt * 16 + lc, gk);
#pragma unroll
        for (int g = 0; g < 3; ++g) bv[g] = lds_frag(ldsB + g * 4096, w * 16 + lc, gk);
#pragma unroll
        for (int g = 0; g < 3; ++g)
#pragma unroll
          for (int mt = 0; mt < 4; ++mt) acc[g][mt] = mfma16(av[mt], bv[g], acc[g][mt]);
      }
    }
    const int col = cg * 64 + w * 16 + lc;
    const float bhr = p.wldbh[col], bhz = p.wldbh[H + col], bhn = p.wldbh[2 * H + col];
    u32* sb = p.segb + (p.t & 1) * SEGSZ;
#pragma unroll
    for (int mt = 0; mt < 4; ++mt)
#pragma unroll
      for (int i = 0; i < 4; ++i) {
        int wrow = rt * 64 + mt * 16 + lr * 4 + i;
        int grow = S + wrow;
        int scen = p.seg[wrow];
        const float* Gr = p.G + scen * TH;
        float r = sigm(Gr[col]       + acc[0][mt][i] + bhr);
        float z = sigm(Gr[H + col]   + acc[1][mt][i] + bhz);
        float n = tanh_(Gr[2*H + col] + r * (acc[2][mt][i] + bhn));
        float h = whfP[grow * H + col];
        float h2 = (1.f - z) * n + z * h;
        whfN[grow * H + col] = h2;
        ringN[grow * H + col] = f2bf(h2);
        atomicMax(sb + scen * H + col, flipf(h2));
      }
  } else {        // ---- sdc GRU ----
    const int ab = b - 496, rh = ab >> 5, cgx = ab & 31;
    const u16* WiT = p.WT;                      // sdc_WiT
    const u16* WhT = p.WT + 1 * TH * H;         // sdc_WhT
    f32x4 ai[3], ah[3];
    f32x4 zero = {0.f, 0.f, 0.f, 0.f};
#pragma unroll
    for (int g = 0; g < 3; ++g) { ai[g] = zero; ah[g] = zero; }

    for (int pass = 0; pass < 2; ++pass) {
      const u32* As = p.segb + ((p.t - 1) & 1) * SEGSZ + rh * 64 * H;
      const u16* Ab = p.ring + tp * SLOT + rh * 64 * H;
      const u16* BT = pass ? WhT : WiT;
      for (int kc = 0; kc < H; kc += 64) {
        __syncthreads();
        if (pass) stage_bf(ldsA, Ab + kc, H, 64, tid);
        else      stage_seg(ldsA, As + kc, H, tid);
#pragma unroll
        for (int g = 0; g < 3; ++g)
          stage_bf(ldsB + g * 1024, BT + (g * H + cgx * 16) * H + kc, H, 16, tid);
        __syncthreads();
#pragma unroll
        for (int s2 = 0; s2 < 2; ++s2) {
          const int gk = s2 * 4 + lr;
          short8 a = lds_frag(ldsA, w * 16 + lc, gk);
#pragma unroll
          for (int g = 0; g < 3; ++g) {
            f32x4 r = pass ? ah[g] : ai[g];
            r = mfma16(a, lds_frag(ldsB + g * 1024, lc, gk), r);
            if (pass) ah[g] = r; else ai[g] = r;
          }
        }
      }
    }
    const int col = cgx * 16 + lc;
    const float bir = p.sdcbi[col], biz = p.sdcbi[H + col], bin = p.sdcbi[2 * H + col];
    const float bhr = p.sdcbh[col], bhz = p.sdcbh[H + col], bhn = p.sdcbh[2 * H + col];
#pragma unroll
    for (int i = 0; i < 4; ++i) {
      int srow = rh * 64 + w * 16 + lr * 4 + i;
      float r = sigm(ai[0][i] + bir + ah[0][i] + bhr);
      float z = sigm(ai[1][i] + biz + ah[1][i] + bhz);
      float n = tanh_(ai[2][i] + bin + r * (ah[2][i] + bhn));
      float h = whfP[srow * H + col];
      float h2 = (1.f - z) * n + z * h;
      whfN[srow * H + col] = h2;
      ringN[srow * H + col] = f2bf(h2);
    }
  }
}

// ---------------------------------------------------------------------------
// k_mlp(jbase): out[:, jbase+slot, :] = leaky(h@o1+b1, .1)@o2 + b2 for 8 slots.
// Grid 1024 (8 slots x 128 row-blocks of 32).
// ---------------------------------------------------------------------------
__global__ __launch_bounds__(256) void k_mlp(P p) {
  const int b = blockIdx.x, tid = threadIdx.x;
  const int slot = b >> 7, rb = b & 127;
  const bool sdc = rb < 4;
  const int r0 = rb * 32, ts = p.t + slot;
  const int w = tid >> 6, lr = (tid >> 4) & 3, lc = tid & 15;
  __shared__ u16 ldsA[32 * 32];
  __shared__ u16 ldsB[512 * 32];
  __shared__ float red[4][32][2];
  const u16* A  = p.ring + slot * SLOT + r0 * H;
  const u16* o1 = p.o1T + (sdc ? 0 : 1) * H * H;
  const float* o1b = sdc ? p.sdco1b : p.wldo1b;
  const float* o2W = sdc ? p.sdco2W : p.wldo2W;
  const float* o2b = sdc ? p.sdco2b : p.wldo2b;

  f32x4 acc[2][8];
  f32x4 zero = {0.f, 0.f, 0.f, 0.f};
#pragma unroll
  for (int mt = 0; mt < 2; ++mt)
#pragma unroll
    for (int j = 0; j < 8; ++j) acc[mt][j] = zero;

  for (int kc = 0; kc < H; kc += 32) {
    __syncthreads();
    stage_bf32(ldsA, A + kc, H, 32, tid);
    stage_bf32(ldsB, o1 + kc, H, 512, tid);
    __syncthreads();
    const int gk = lr;
    short8 av[2], bv[8];
#pragma unroll
    for (int mt = 0; mt < 2; ++mt) av[mt] = lds_frag32(ldsA, mt * 16 + lc, gk);
#pragma unroll
    for (int j = 0; j < 8; ++j) bv[j] = lds_frag32(ldsB, (w * 8 + j) * 16 + lc, gk);
#pragma unroll
    for (int mt = 0; mt < 2; ++mt)
#pragma unroll
      for (int j = 0; j < 8; ++j) acc[mt][j] = mfma16(av[mt], bv[j], acc[mt][j]);
  }
  float pr[2][4][2];
#pragma unroll
  for (int mt = 0; mt < 2; ++mt)
#pragma unroll
    for (int i = 0; i < 4; ++i) { pr[mt][i][0] = 0.f; pr[mt][i][1] = 0.f; }
#pragma unroll
  for (int mt = 0; mt < 2; ++mt)
#pragma unroll
    for (int j = 0; j < 8; ++j) {
      int colj = (w * 8 + j) * 16 + lc;
      float w0 = o2W[colj * 2], w1 = o2W[colj * 2 + 1], b1v = o1b[colj];
#pragma unroll
      for (int i = 0; i < 4; ++i) {
        float v = acc[mt][j][i] + b1v;
        v = v > 0.f ? v : 0.1f * v;
        pr[mt][i][0] += v * w0;
        pr[mt][i][1] += v * w1;
      }
    }
#pragma unroll
  for (int off = 1; off < 16; off <<= 1)
#pragma unroll
    for (int mt = 0; mt < 2; ++mt)
#pragma unroll
      for (int i = 0; i < 4; ++i) {
        pr[mt][i][0] += __shfl_xor(pr[mt][i][0], off);
        pr[mt][i][1] += __shfl_xor(pr[mt][i][1], off);
      }
  if (lc == 0) {
#pragma unroll
    for (int mt = 0; mt < 2; ++mt)
#pragma unroll
      for (int i = 0; i < 4; ++i) {
        red[w][mt * 16 + lr * 4 + i][0] = pr[mt][i][0];
        red[w][mt * 16 + lr * 4 + i][1] = pr[mt][i][1];
      }
  }
  __syncthreads();
  if (tid < 64) {
    int row = tid >> 1, od = tid & 1;
    float sum2 = red[0][row][od] + red[1][row][od] + red[2][row][od] + red[3][row][od] + o2b[od];
    p.out[(r0 + row) * 160 + ts * 2 + od] = sum2;
  }
}

// ---------------------------------------------------------------------------
extern "C" void kernel_launch(void* const* d_in, const int* in_sizes, int n_in,
                              void* d_out, int out_size, void* d_ws, size_t ws_size,
                              hipStream_t stream) {
  P prm;
  prm.goals  = (const float*)d_in[0];
  prm.dyn    = (const float*)d_in[1];
  prm.ccls   = (const float*)d_in[2];
  prm.inte   = (const float*)d_in[3];
  prm.seg    = (const int*)  d_in[4];
  prm.sdc_h0 = (const float*)d_in[5];
  prm.wld_h0 = (const float*)d_in[6];
  prm.golW   = (const float*)d_in[7];
  prm.golb   = (const float*)d_in[8];
  prm.sdcWi  = (const float*)d_in[9];
  prm.sdcWh  = (const float*)d_in[10];
  prm.sdcbi  = (const float*)d_in[11];
  prm.sdcbh  = (const float*)d_in[12];
  prm.wldWi  = (const float*)d_in[13];
  prm.wldWh  = (const float*)d_in[14];
  prm.wldbi  = (const float*)d_in[15];
  prm.wldbh  = (const float*)d_in[16];
  prm.sdco1W = (const float*)d_in[17];
  prm.sdco1b = (const float*)d_in[18];
  prm.sdco2W = (const float*)d_in[19];
  prm.sdco2b = (const float*)d_in[20];
  prm.wldo1W = (const float*)d_in[21];
  prm.wldo1b = (const float*)d_in[22];
  prm.wldo2W = (const float*)d_in[23];
  prm.wldo2b = (const float*)d_in[24];
  prm.out = (float*)d_out;

  char* ws = (char*)d_ws;
  prm.whf  = (float*)(ws + 0);            // 16,777,216 B
  prm.ring = (u16*)  (ws + 16777216);     // 33,554,432 B
  prm.enc  = (u16*)  (ws + 50331648);     //  4,194,304 B
  prm.WT   = (u16*)  (ws + 54525952);     //  6,291,456 B
  prm.o1T  = (u16*)  (ws + 60817408);     //  1,048,576 B
  prm.G    = (float*)(ws + 61865984);     //    786,432 B
  prm.segb = (u32*)  (ws + 62652416);     //    524,288 B  (total ~63.2 MB)

  prm.t = 0;
  k_prep<<<1028, 256, 0, stream>>>(prm);
  k_big0<<<512, 256, 0, stream>>>(prm);
  for (int t = 1; t < 80; ++t) {
    prm.t = t;
    k_small<<<64, 256, 0, stream>>>(prm);
    k_big<<<560, 256, 0, stream>>>(prm);
    if ((t & 7) == 7) {
      P pm = prm;
      pm.t = t - 7;
      k_mlp<<<1024, 256, 0, stream>>>(pm);
    }
  }
}

// Round 2
// 3128.065 us; speedup vs baseline: 1.6560x; 1.6560x over previous
//
#include <hip/hip_runtime.h>

// ---------------------------------------------------------------------------
// arGDPmax_net: 80-step coupled GRU (SDC 128 / world 3968 rows, H=512)
// + segment-max coupling + per-step MLP head.
//
// Round-2 changes vs round-1 (which passed at 5180us, absmax 0.0195):
//  - All GEMM staging converted to __builtin_amdgcn_global_load_lds width=16
//    (m97 structure): linear LDS dest, XOR-16B-swizzled GLOBAL source, so
//    ds_read_b128 fragment reads stay 2-way-max on banks (free).
//  - k_small: plain 64x64-tile GEMM (48 blocks) + segb clear + segb->bf16
//    conversion (segbf) so k_big's sdc pass uses the same bf16 staging.
//  - k_mlp: 128x128-tile GEMM, BK=64, fused leaky+layer2 partials, plus a
//    tiny deterministic k_mlp2 reduction (no float atomics).
//  - world epilogue: run-length merge of same-scenario rows before atomicMax.
// ---------------------------------------------------------------------------

typedef __attribute__((ext_vector_type(8))) short short8;
typedef __attribute__((ext_vector_type(4))) float f32x4;
typedef unsigned short u16;
typedef unsigned int u32;

#define DEV __device__ __forceinline__

constexpr int S  = 128;
constexpr int NR = 4096;
constexpr int H  = 512;
constexpr int TH = 1536;
constexpr int SLOT = NR * H;
constexpr int SEGSZ = S * H;

struct P {
  const float *goals, *dyn, *ccls, *inte;
  const int *seg;
  const float *sdc_h0, *wld_h0;
  const float *golW, *golb;
  const float *sdcbi, *sdcbh, *wldbi, *wldbh;
  const float *sdco1b, *sdco2W, *sdco2b;
  const float *wldo1b, *wldo2W, *wldo2b;
  const float *sdcWi, *sdcWh, *wldWi, *wldWh, *sdco1W, *wldo1W;
  float *out;
  float *whf;      // [2][4096][512] f32 carried state
  u16   *ring;     // [8][4096][512] bf16 state history
  u16   *enc;      // [4096][512] bf16 encoder output (aliased after t=0)
  u16   *WT;       // 4 x [1536][512] bf16: sdcWiT, sdcWhT, wldWiT, wldWhT
  u16   *o1T;      // 2 x [512][512] bf16
  float *G;        // [128][1536] f32: sh@wld_Wi + bi
  u32   *segb;     // [2][128][512] flipped-uint segmax buffers
  u16   *segbf;    // [128][512] bf16 of prev-step segmax (aliases enc)
  float *part;     // [4][32768][2] f32 MLP layer-2 partials (aliases enc+128KB)
  int t;
};

DEV u16 f2bf(float f) {
  u32 u = __float_as_uint(f);
  u32 r = u + 0x7FFFu + ((u >> 16) & 1u);
  return (u16)(r >> 16);
}
DEV u32 flipf(float f) {
  u32 u = __float_as_uint(f);
  return (u & 0x80000000u) ? ~u : (u | 0x80000000u);
}
DEV float unflip(u32 s) {
  u32 u = (s & 0x80000000u) ? (s & 0x7FFFFFFFu) : ~s;
  return __uint_as_float(u);
}
DEV float sigm(float x)  { return 1.0f / (1.0f + __expf(-x)); }
DEV float tanh_(float x) { return 2.0f / (1.0f + __expf(-2.0f * x)) - 1.0f; }

DEV f32x4 mfma16(short8 a, short8 b, f32x4 c) {
  return __builtin_amdgcn_mfma_f32_16x16x32_bf16(a, b, c, 0, 0, 0);
}

// async global->LDS, 16B per lane. LDS dest = wave-uniform base + lane*16.
DEV void gload16(const void* g, void* l) {
  __builtin_amdgcn_global_load_lds(
      (const __attribute__((address_space(1))) void*)g,
      (__attribute__((address_space(3))) void*)l, 16, 0, 0);
}

// reg-staged variant (k_prep/k_big0 sdc paths). LDS (m,g) <- src (m, g^(m&7)).
DEV void stage_bf(u16* lds, const u16* src, int stride, int rows, int tid) {
  for (int u = tid; u < rows * 8; u += 256) {
    int m = u >> 3, g = u & 7, gs = g ^ (m & 7);
    *(short8*)(lds + (u << 3)) = *(const short8*)(src + m * stride + (gs << 3));
  }
}
// fragment read honoring the swizzle; row stride 64 elems (128B).
DEV short8 lds_frag(const u16* lds, int row, int g) {
  return *(const short8*)(lds + row * 64 + ((g ^ (row & 7)) << 3));
}

// ---------------------------------------------------------------------------
// k_prep: weight transposes, encoder, h0 copy, segbuf[0] clear. Grid 1028.
// ---------------------------------------------------------------------------
__global__ __launch_bounds__(256) void k_prep(P p) {
  const int b = blockIdx.x, tid = threadIdx.x;
  __shared__ u16 lt[64 * 72];
  if (b < 896) {
    int nt, kt, Nn; const float* src; u16* dst;
    if (b < 768) {
      int m = b / 192, t2 = b % 192;
      nt = t2 % 24; kt = t2 / 24; Nn = TH;
      src = (m == 0) ? p.sdcWi : (m == 1) ? p.sdcWh : (m == 2) ? p.wldWi : p.wldWh;
      dst = p.WT + m * TH * H;
    } else {
      int bb = b - 768, m = bb / 64, t2 = bb % 64;
      nt = t2 % 8; kt = t2 / 8; Nn = H;
      src = m ? p.wldo1W : p.sdco1W;
      dst = p.o1T + m * H * H;
    }
    for (int it = 0; it < 16; ++it) {
      int kl = it * 4 + (tid >> 6), nl = tid & 63;
      lt[nl * 72 + kl] = f2bf(src[(kt * 64 + kl) * Nn + nt * 64 + nl]);
    }
    __syncthreads();
    for (int it = 0; it < 2; ++it) {
      int nl = it * 32 + (tid >> 3), k8 = (tid & 7) * 8;
      *(short8*)(dst + (nt * 64 + nl) * H + kt * 64 + k8) =
          *(const short8*)(lt + nl * 72 + k8);
    }
  } else if (b < 960) {
    int r0 = (b - 896) * 64;
    for (int i = 0; i < 128; ++i) {
      int idx = i * 256 + tid, row = r0 + (idx >> 9), c = idx & 511;
      float v;
      if (c < 128)      v = p.goals[row*2]*p.golW[c] + p.goals[row*2+1]*p.golW[128+c] + p.golb[c];
      else if (c < 256) v = p.dyn [row*128 + c - 128];
      else if (c < 384) v = p.ccls[row*128 + c - 256];
      else              v = p.inte[row*128 + c - 384];
      p.enc[row * H + c] = f2bf(v);
    }
  } else if (b < 1024) {
    int r0 = (b - 960) * 64;
    for (int i = 0; i < 128; ++i) {
      int idx = i * 256 + tid, row = r0 + (idx >> 9), c = idx & 511;
      float v = (row < S) ? p.sdc_h0[row * H + c] : p.wld_h0[(row - S) * H + c];
      p.whf[SLOT + row * H + c] = v;
      p.ring[7 * SLOT + row * H + c] = f2bf(v);
    }
  } else {
    int base = (b - 1024) * 16384;
    for (int i = 0; i < 64; ++i) p.segb[base + i * 256 + tid] = 0u;
  }
}

// ---------------------------------------------------------------------------
// k_big0: step 0 (full gi + gh for all 4096 rows). Grid 512 (64 rt x 8 cg).
// Reg-staged (runs once; not worth converting).
// ---------------------------------------------------------------------------
__global__ __launch_bounds__(256) void k_big0(P p) {
  const int b = blockIdx.x, tid = threadIdx.x;
  const int rt = b >> 3, cg = b & 7;
  const bool sdc = rt < 2;
  const int w = tid >> 6, lr = (tid >> 4) & 3, lc = tid & 15;
  __shared__ u16 ldsA[4096];
  __shared__ u16 ldsB[12288];
  const u16* WiT = p.WT + (sdc ? 0 : 2) * TH * H;
  const u16* WhT = p.WT + (sdc ? 1 : 3) * TH * H;

  f32x4 ai[3][4], ah[3][4];
  f32x4 zero = {0.f, 0.f, 0.f, 0.f};
#pragma unroll
  for (int g = 0; g < 3; ++g)
#pragma unroll
    for (int mt = 0; mt < 4; ++mt) { ai[g][mt] = zero; ah[g][mt] = zero; }

  for (int pass = 0; pass < 2; ++pass) {
    const u16* A  = pass ? (p.ring + 7 * SLOT + rt * 64 * H) : (p.enc + rt * 64 * H);
    const u16* BT = pass ? WhT : WiT;
    for (int kc = 0; kc < H; kc += 64) {
      __syncthreads();
      stage_bf(ldsA, A + kc, H, 64, tid);
#pragma unroll
      for (int g = 0; g < 3; ++g)
        stage_bf(ldsB + g * 4096, BT + (g * H + cg * 64) * H + kc, H, 64, tid);
      __syncthreads();
#pragma unroll
      for (int s2 = 0; s2 < 2; ++s2) {
        const int gk = s2 * 4 + lr;
        short8 av[4], bv[3];
#pragma unroll
        for (int mt = 0; mt < 4; ++mt) av[mt] = lds_frag(ldsA, mt * 16 + lc, gk);
#pragma unroll
        for (int g = 0; g < 3; ++g) bv[g] = lds_frag(ldsB + g * 4096, w * 16 + lc, gk);
#pragma unroll
        for (int g = 0; g < 3; ++g)
#pragma unroll
          for (int mt = 0; mt < 4; ++mt) {
            f32x4 r = pass ? ah[g][mt] : ai[g][mt];
            r = mfma16(av[mt], bv[g], r);
            if (pass) ah[g][mt] = r; else ai[g][mt] = r;
          }
      }
    }
  }
  const float* bi = sdc ? p.sdcbi : p.wldbi;
  const float* bh = sdc ? p.sdcbh : p.wldbh;
  const int col = cg * 64 + w * 16 + lc;
  const float bir = bi[col], biz = bi[H + col], bin = bi[2 * H + col];
  const float bhr = bh[col], bhz = bh[H + col], bhn = bh[2 * H + col];
#pragma unroll
  for (int mt = 0; mt < 4; ++mt)
#pragma unroll
    for (int i = 0; i < 4; ++i) {
      int grow = rt * 64 + mt * 16 + lr * 4 + i;
      float r = sigm(ai[0][mt][i] + bir + ah[0][mt][i] + bhr);
      float z = sigm(ai[1][mt][i] + biz + ah[1][mt][i] + bhz);
      float n = tanh_(ai[2][mt][i] + bin + r * (ah[2][mt][i] + bhn));
      float h = p.whf[SLOT + grow * H + col];
      float h2 = (1.f - z) * n + z * h;
      p.whf[grow * H + col] = h2;
      p.ring[grow * H + col] = f2bf(h2);
      if (!sdc) {
        int scen = p.seg[grow - S];
        atomicMax(p.segb + scen * H + col, flipf(h2));
      }
    }
}

// ---------------------------------------------------------------------------
// k_small(t): clear segb[t&1]; segbf = bf16(unflip(segb[(t-1)&1]));
//             G = sh_{t-1} @ wld_WiT + bi  (128x1536, 48 blocks of 64x64).
// ---------------------------------------------------------------------------
__global__ __launch_bounds__(256) void k_small(P p) {
  const int b = blockIdx.x, tid = threadIdx.x;
  const int gtid = b * 256 + tid;
  // (a) clear this step's segmax buffer
  u32* sb = p.segb + (p.t & 1) * SEGSZ;
  for (int i = gtid; i < 16384; i += 12288)
    ((uint4*)sb)[i] = make_uint4(0u, 0u, 0u, 0u);
  // (b) convert previous step's segmax to bf16 for k_big's sdc staging
  const u32* sp = p.segb + ((p.t - 1) & 1) * SEGSZ;
  for (int i = gtid; i < 16384; i += 12288) {
    uint4 q = ((const uint4*)sp)[i];
    u32 lo = (u32)f2bf(unflip(q.x)) | ((u32)f2bf(unflip(q.y)) << 16);
    u32 hi = (u32)f2bf(unflip(q.z)) | ((u32)f2bf(unflip(q.w)) << 16);
    ((u32*)p.segbf)[i * 2]     = lo;
    ((u32*)p.segbf)[i * 2 + 1] = hi;
  }
  // (c) G GEMM: 64x64 tile, gload_lds staging
  const int rh = b / 24, nc = b % 24;
  const int w = tid >> 6, lr = (tid >> 4) & 3, lc = tid & 15;
  __shared__ u16 sm[8192];            // A 512 units + B 512 units
  const u16* Ab = p.ring + ((p.t - 1) & 7) * SLOT + rh * 64 * H;
  const u16* Wb = p.WT + 2 * TH * H;  // wld_WiT

  f32x4 acc[4];
  f32x4 zero = {0.f, 0.f, 0.f, 0.f};
#pragma unroll
  for (int mt = 0; mt < 4; ++mt) acc[mt] = zero;

  for (int kc = 0; kc < H; kc += 64) {
    __syncthreads();
#pragma unroll
    for (int it = 0; it < 4; ++it) {
      int u = it * 256 + tid;
      int gs = (u ^ (u >> 3)) & 7;
      const u16* src;
      if (u < 512) src = Ab + (u >> 3) * H + kc + gs * 8;
      else         src = Wb + (nc * 64 + ((u >> 3) & 63)) * H + kc + gs * 8;
      gload16(src, sm + (it * 256 + (tid & 192)) * 8);
    }
    __syncthreads();
#pragma unroll
    for (int s2 = 0; s2 < 2; ++s2) {
      const int gk = s2 * 4 + lr;
      short8 bv = lds_frag(sm + 4096, w * 16 + lc, gk);
#pragma unroll
      for (int mt = 0; mt < 4; ++mt)
        acc[mt] = mfma16(lds_frag(sm, mt * 16 + lc, gk), bv, acc[mt]);
    }
  }
  const int colb = nc * 64 + w * 16 + lc;
  const float bi = p.wldbi[colb];
#pragma unroll
  for (int mt = 0; mt < 4; ++mt)
#pragma unroll
    for (int i = 0; i < 4; ++i)
      p.G[(rh * 64 + mt * 16 + lr * 4 + i) * TH + colb] = acc[mt][i] + bi;
}

// ---------------------------------------------------------------------------
// k_big(t): blocks 0..495: world GRU (64x192 tile, gload_lds, gather(G),
//           gates, run-length-merged segmax atomics).
//           blocks 496..559: sdc GRU (reg-staged; A from segbf + ring).
// ---------------------------------------------------------------------------
__global__ __launch_bounds__(256) void k_big(P p) {
  const int b = blockIdx.x, tid = threadIdx.x;
  const int w = tid >> 6, lr = (tid >> 4) & 3, lc = tid & 15;
  __shared__ u16 sm[16384];           // 32 KB
  const int tp = (p.t - 1) & 7, tn = p.t & 7;
  const float* whfP = p.whf + ((p.t - 1) & 1) * SLOT;
  float* whfN = p.whf + (p.t & 1) * SLOT;
  u16* ringN = p.ring + tn * SLOT;

  if (b < 496) {  // ---- world GRU ----
    const int rt = b / 8, cg = b % 8;
    const u16* Abase = p.ring + tp * SLOT + (S + rt * 64) * H;
    const u16* Bbase = p.WT + 3 * TH * H;      // wld_WhT
    f32x4 acc[3][4];
    f32x4 zero = {0.f, 0.f, 0.f, 0.f};
#pragma unroll
    for (int g = 0; g < 3; ++g)
#pragma unroll
      for (int mt = 0; mt < 4; ++mt) acc[g][mt] = zero;

    for (int kc = 0; kc < H; kc += 64) {
      __syncthreads();
#pragma unroll
      for (int it = 0; it < 8; ++it) {
        int u = it * 256 + tid;
        int gs = (u ^ (u >> 3)) & 7;
        const u16* src;
        if (u < 512) {
          src = Abase + (u >> 3) * H + kc + gs * 8;
        } else {
          int v = u - 512;
          int g = v >> 9, m = (v >> 3) & 63;
          src = Bbase + (g * H + cg * 64 + m) * H + kc + gs * 8;
        }
        gload16(src, sm + (it * 256 + (tid & 192)) * 8);
      }
      __syncthreads();
#pragma unroll
      for (int s2 = 0; s2 < 2; ++s2) {
        const int gk = s2 * 4 + lr;
        short8 av[4], bv[3];
#pragma unroll
        for (int mt = 0; mt < 4; ++mt) av[mt] = lds_frag(sm, mt * 16 + lc, gk);
#pragma unroll
        for (int g = 0; g < 3; ++g) bv[g] = lds_frag(sm + 4096 + g * 4096, w * 16 + lc, gk);
#pragma unroll
        for (int g = 0; g < 3; ++g)
#pragma unroll
          for (int mt = 0; mt < 4; ++mt) acc[g][mt] = mfma16(av[mt], bv[g], acc[g][mt]);
      }
    }
    const int col = cg * 64 + w * 16 + lc;
    const float bhr = p.wldbh[col], bhz = p.wldbh[H + col], bhn = p.wldbh[2 * H + col];
    u32* sb = p.segb + (p.t & 1) * SEGSZ;
    int curSc = -1; float curMx = 0.f;
#pragma unroll
    for (int mt = 0; mt < 4; ++mt)
#pragma unroll
      for (int i = 0; i < 4; ++i) {
        int wrow = rt * 64 + mt * 16 + lr * 4 + i;
        int grow = S + wrow;
        int scen = p.seg[wrow];
        const float* Gr = p.G + scen * TH;
        float r = sigm(Gr[col]         + acc[0][mt][i] + bhr);
        float z = sigm(Gr[H + col]     + acc[1][mt][i] + bhz);
        float n = tanh_(Gr[2 * H + col] + r * (acc[2][mt][i] + bhn));
        float h = whfP[grow * H + col];
        float h2 = (1.f - z) * n + z * h;
        whfN[grow * H + col] = h2;
        ringN[grow * H + col] = f2bf(h2);
        if (scen == curSc) curMx = fmaxf(curMx, h2);
        else {
          if (curSc >= 0) atomicMax(sb + curSc * H + col, flipf(curMx));
          curSc = scen; curMx = h2;
        }
      }
    atomicMax(sb + curSc * H + col, flipf(curMx));
  } else {        // ---- sdc GRU (64 blocks of 64 rows x 48 gate-paired cols) ----
    const int ab = b - 496, rh = ab >> 5, cgx = ab & 31;
    const u16* WiT = p.WT;
    const u16* WhT = p.WT + 1 * TH * H;
    u16* ldsA = sm;                     // 64x64
    u16* ldsB = sm + 4096;              // 3 x 16x64
    f32x4 ai[3], ah[3];
    f32x4 zero = {0.f, 0.f, 0.f, 0.f};
#pragma unroll
    for (int g = 0; g < 3; ++g) { ai[g] = zero; ah[g] = zero; }

    for (int pass = 0; pass < 2; ++pass) {
      const u16* A  = pass ? (p.ring + tp * SLOT + rh * 64 * H) : (p.segbf + rh * 64 * H);
      const u16* BT = pass ? WhT : WiT;
      for (int kc = 0; kc < H; kc += 64) {
        __syncthreads();
        stage_bf(ldsA, A + kc, H, 64, tid);
#pragma unroll
        for (int g = 0; g < 3; ++g)
          stage_bf(ldsB + g * 1024, BT + (g * H + cgx * 16) * H + kc, H, 16, tid);
        __syncthreads();
#pragma unroll
        for (int s2 = 0; s2 < 2; ++s2) {
          const int gk = s2 * 4 + lr;
          short8 a = lds_frag(ldsA, w * 16 + lc, gk);
#pragma unroll
          for (int g = 0; g < 3; ++g) {
            f32x4 r = pass ? ah[g] : ai[g];
            r = mfma16(a, lds_frag(ldsB + g * 1024, lc, gk), r);
            if (pass) ah[g] = r; else ai[g] = r;
          }
        }
      }
    }
    const int col = cgx * 16 + lc;
    const float bir = p.sdcbi[col], biz = p.sdcbi[H + col], bin = p.sdcbi[2 * H + col];
    const float bhr = p.sdcbh[col], bhz = p.sdcbh[H + col], bhn = p.sdcbh[2 * H + col];
#pragma unroll
    for (int i = 0; i < 4; ++i) {
      int srow = rh * 64 + w * 16 + lr * 4 + i;
      float r = sigm(ai[0][i] + bir + ah[0][i] + bhr);
      float z = sigm(ai[1][i] + biz + ah[1][i] + bhz);
      float n = tanh_(ai[2][i] + bin + r * (ah[2][i] + bhn));
      float h = whfP[srow * H + col];
      float h2 = (1.f - z) * n + z * h;
      whfN[srow * H + col] = h2;
      ringN[srow * H + col] = f2bf(h2);
    }
  }
}

// ---------------------------------------------------------------------------
// k_mlp: per 8-slot batch, layer1 GEMM (128x128 tiles) + fused leaky+layer2
// -> partial sums per col-quarter.  Grid 1024 = (8 slot x 32 rtile) x 4 ct.
// ---------------------------------------------------------------------------
__global__ __launch_bounds__(256) void k_mlp(P p) {
  const int b = blockIdx.x, tid = threadIdx.x;
  const int rt = b >> 2, ct = b & 3;
  const int slot = rt >> 5, rtile = rt & 31;
  const bool sdc = (rtile == 0);
  const int w = tid >> 6, lr = (tid >> 4) & 3, lc = tid & 15;
  __shared__ u16 sm[16384];           // A 128x64 + B 128x64
  const u16* A  = p.ring + slot * SLOT + rtile * 128 * H;
  const u16* Bb = p.o1T + (sdc ? 0 : 1) * H * H + (ct * 128) * H;
  const float* o1b = sdc ? p.sdco1b : p.wldo1b;
  const float* o2W = sdc ? p.sdco2W : p.wldo2W;

  f32x4 acc[8][2];
  f32x4 zero = {0.f, 0.f, 0.f, 0.f};
#pragma unroll
  for (int mt = 0; mt < 8; ++mt) { acc[mt][0] = zero; acc[mt][1] = zero; }

  for (int kc = 0; kc < H; kc += 64) {
    __syncthreads();
#pragma unroll
    for (int it = 0; it < 8; ++it) {
      int u = it * 256 + tid;
      int gs = (u ^ (u >> 3)) & 7;
      const u16* src;
      if (u < 1024) src = A  + (u >> 3) * H + kc + gs * 8;
      else          src = Bb + ((u >> 3) & 127) * H + kc + gs * 8;
      gload16(src, sm + (it * 256 + (tid & 192)) * 8);
    }
    __syncthreads();
#pragma unroll
    for (int s2 = 0; s2 < 2; ++s2) {
      const int gk = s2 * 4 + lr;
      short8 av[8], bv[2];
#pragma unroll
      for (int mt = 0; mt < 8; ++mt) av[mt] = lds_frag(sm, mt * 16 + lc, gk);
#pragma unroll
      for (int c2 = 0; c2 < 2; ++c2) bv[c2] = lds_frag(sm + 8192, w * 32 + c2 * 16 + lc, gk);
#pragma unroll
      for (int mt = 0; mt < 8; ++mt)
#pragma unroll
        for (int c2 = 0; c2 < 2; ++c2) acc[mt][c2] = mfma16(av[mt], bv[c2], acc[mt][c2]);
    }
  }
  __syncthreads();                     // reuse sm as float red[4][128][2]
  float* red = (float*)sm;
#pragma unroll
  for (int mt = 0; mt < 8; ++mt) {
    float q0[4] = {0.f, 0.f, 0.f, 0.f}, q1[4] = {0.f, 0.f, 0.f, 0.f};
#pragma unroll
    for (int c2 = 0; c2 < 2; ++c2) {
      int col = ct * 128 + w * 32 + c2 * 16 + lc;
      float b1 = o1b[col], w0 = o2W[col * 2], w1 = o2W[col * 2 + 1];
#pragma unroll
      for (int i = 0; i < 4; ++i) {
        float v = acc[mt][c2][i] + b1;
        v = v > 0.f ? v : 0.1f * v;
        q0[i] += v * w0; q1[i] += v * w1;
      }
    }
#pragma unroll
    for (int off = 1; off < 16; off <<= 1)
#pragma unroll
      for (int i = 0; i < 4; ++i) {
        q0[i] += __shfl_xor(q0[i], off);
        q1[i] += __shfl_xor(q1[i], off);
      }
    if (lc == 0)
#pragma unroll
      for (int i = 0; i < 4; ++i) {
        int row = mt * 16 + lr * 4 + i;
        red[(w * 128 + row) * 2 + 0] = q0[i];
        red[(w * 128 + row) * 2 + 1] = q1[i];
      }
  }
  __syncthreads();
  {
    int row = tid >> 1, od = tid & 1;
    float sum = red[(0 * 128 + row) * 2 + od] + red[(1 * 128 + row) * 2 + od] +
                red[(2 * 128 + row) * 2 + od] + red[(3 * 128 + row) * 2 + od];
    int r = slot * 4096 + rtile * 128 + row;
    p.part[ct * 65536 + r * 2 + od] = sum;
  }
}

// k_mlp2: out = sum of 4 col-quarter partials + o2 bias. Grid 64.
__global__ __launch_bounds__(256) void k_mlp2(P p) {
  const int gtid = blockIdx.x * 256 + threadIdx.x;
  for (int i = gtid; i < 65536; i += 16384) {
    int r = i >> 1, od = i & 1;
    int row = r & 4095, slot = r >> 12;
    float v = p.part[i] + p.part[65536 + i] + p.part[131072 + i] + p.part[196608 + i];
    v += (row < S ? p.sdco2b : p.wldo2b)[od];
    p.out[row * 160 + (p.t + slot) * 2 + od] = v;
  }
}

// ---------------------------------------------------------------------------
extern "C" void kernel_launch(void* const* d_in, const int* in_sizes, int n_in,
                              void* d_out, int out_size, void* d_ws, size_t ws_size,
                              hipStream_t stream) {
  P prm;
  prm.goals  = (const float*)d_in[0];
  prm.dyn    = (const float*)d_in[1];
  prm.ccls   = (const float*)d_in[2];
  prm.inte   = (const float*)d_in[3];
  prm.seg    = (const int*)  d_in[4];
  prm.sdc_h0 = (const float*)d_in[5];
  prm.wld_h0 = (const float*)d_in[6];
  prm.golW   = (const float*)d_in[7];
  prm.golb   = (const float*)d_in[8];
  prm.sdcWi  = (const float*)d_in[9];
  prm.sdcWh  = (const float*)d_in[10];
  prm.sdcbi  = (const float*)d_in[11];
  prm.sdcbh  = (const float*)d_in[12];
  prm.wldWi  = (const float*)d_in[13];
  prm.wldWh  = (const float*)d_in[14];
  prm.wldbi  = (const float*)d_in[15];
  prm.wldbh  = (const float*)d_in[16];
  prm.sdco1W = (const float*)d_in[17];
  prm.sdco1b = (const float*)d_in[18];
  prm.sdco2W = (const float*)d_in[19];
  prm.sdco2b = (const float*)d_in[20];
  prm.wldo1W = (const float*)d_in[21];
  prm.wldo1b = (const float*)d_in[22];
  prm.wldo2W = (const float*)d_in[23];
  prm.wldo2b = (const float*)d_in[24];
  prm.out = (float*)d_out;

  char* ws = (char*)d_ws;
  prm.whf   = (float*)(ws + 0);            // 16,777,216 B
  prm.ring  = (u16*)  (ws + 16777216);     // 33,554,432 B
  prm.enc   = (u16*)  (ws + 50331648);     //  4,194,304 B
  prm.WT    = (u16*)  (ws + 54525952);     //  6,291,456 B
  prm.o1T   = (u16*)  (ws + 60817408);     //  1,048,576 B
  prm.G     = (float*)(ws + 61865984);     //    786,432 B
  prm.segb  = (u32*)  (ws + 62652416);     //    524,288 B (total ~63.2 MB)
  prm.segbf = (u16*)  (ws + 50331648);           // aliases enc (dead after t=0)
  prm.part  = (float*)(ws + 50331648 + 131072);  // aliases enc+128KB (1 MB)

  prm.t = 0;
  k_prep<<<1028, 256, 0, stream>>>(prm);
  k_big0<<<512, 256, 0, stream>>>(prm);
  for (int t = 1; t < 80; ++t) {
    prm.t = t;
    k_small<<<48, 256, 0, stream>>>(prm);
    k_big<<<560, 256, 0, stream>>>(prm);
    if ((t & 7) == 7) {
      P pm = prm;
      pm.t = t - 7;
      k_mlp<<<1024, 256, 0, stream>>>(pm);
      k_mlp2<<<64, 256, 0, stream>>>(pm);
    }
  }
}